// Round 4
// baseline (122.416 us; speedup 1.0000x reference)
//
#include <hip/hip_runtime.h>
#include <stdint.h>

// DepthAttentionResidual: S=16, B=4, T=1024, D=2048, fp32 in/out.
// Persistent-block pipelined version:
//   256 blocks (1/CU, pinned by 128 KB LDS) x 1024 threads (16 waves).
//   Each block processes 16 consecutive (b,t) tiles. Per tile:
//     - scores (RMSNorm dot q) computed from fp32 registers during load pass
//     - fp16-staged into double-buffered LDS (2 x 64 KB)
//     - next tile's global loads issued right AFTER the barrier, so in-flight
//       vmem never crosses a barrier drain; they complete under softmax+mix
//       of the current tile and the next tile's score pass.

#define NSRC  16
#define NB    4
#define NT    1024
#define ND    2048
#define TILES 16        // (NB*NT) / NBLK
#define NBLK  256

typedef __fp16 half2_t __attribute__((ext_vector_type(2)));

__global__ __launch_bounds__(1024, 4)
void dar_persist_kernel(const float* __restrict__ q,
                        const float* __restrict__ bank,
                        float* __restrict__ out) {
    __shared__ __align__(16) uint32_t buf[2][NSRC][ND / 2];  // fp16x2, 64 KB per buffer
    __shared__ float s_sc[2][NSRC];

    const int tid  = threadIdx.x;
    const int wave = tid >> 6;      // source index owned by this wave
    const int lane = tid & 63;
    const int bt0  = blockIdx.x * TILES;

    // Hoist q into registers (same d-slice every tile).
    const float4* q4 = reinterpret_cast<const float4*>(q);
    float4 qr[8];
    #pragma unroll
    for (int i = 0; i < 8; ++i) qr[i] = q4[i * 64 + lane];

    // Base of this wave's source rows for this block's tile range.
    const float4* srcbase = reinterpret_cast<const float4*>(bank)
                          + ((size_t)wave * (NB * NT) + bt0) * (ND / 4);

    float4 rA[8], rB[8];
    #pragma unroll
    for (int i = 0; i < 8; ++i) rA[i] = srcbase[i * 64 + lane];  // tile 0

    auto body = [&](int t, float4 (&cur)[8], float4 (&nxt)[8]) {
        const int c  = t & 1;
        const int bt = bt0 + t;

        // ---- scores from registers: p2 = sum x^2, pq = sum q*x ----
        float p2 = 0.0f, pq = 0.0f;
        #pragma unroll
        for (int i = 0; i < 8; ++i) {
            const float4 v = cur[i], qv = qr[i];
            p2 += v.x * v.x + v.y * v.y + v.z * v.z + v.w * v.w;
            pq += qv.x * v.x + qv.y * v.y + qv.z * v.z + qv.w * v.w;
        }
        #pragma unroll
        for (int m = 32; m >= 1; m >>= 1) {
            p2 += __shfl_xor(p2, m, 64);
            pq += __shfl_xor(pq, m, 64);
        }
        if (lane == 0) {
            const float ms = p2 * (1.0f / ND) + 1.1920928955078125e-07f;  // FLT_EPSILON
            s_sc[c][wave]  = pq * rsqrtf(ms) * 0.022097086912079608f;     // 1/sqrt(2048)
        }

        // ---- stage current tile as fp16 into buf[c] ----
        #pragma unroll
        for (int i = 0; i < 8; ++i) {
            const float4 v = cur[i];
            const half2_t lo = __builtin_amdgcn_cvt_pkrtz(v.x, v.y);
            const half2_t hi = __builtin_amdgcn_cvt_pkrtz(v.z, v.w);
            uint2 u;
            u.x = __builtin_bit_cast(uint32_t, lo);
            u.y = __builtin_bit_cast(uint32_t, hi);
            reinterpret_cast<uint2*>(&buf[c][wave][0])[i * 64 + lane] = u;
        }

        __syncthreads();

        // ---- prefetch next tile (post-barrier: vmem never crosses a drain) ----
        if (t + 1 < TILES) {
            const float4* s2 = srcbase + (size_t)(t + 1) * (ND / 4);
            #pragma unroll
            for (int i = 0; i < 8; ++i) nxt[i] = s2[i * 64 + lane];
        }

        // ---- softmax over 16 sources (redundant per thread) ----
        float w[NSRC], mx = -1e30f;
        #pragma unroll
        for (int s = 0; s < NSRC; ++s) { w[s] = s_sc[c][s]; mx = fmaxf(mx, w[s]); }
        float sum = 0.0f;
        #pragma unroll
        for (int s = 0; s < NSRC; ++s) { w[s] = __expf(w[s] - mx); sum += w[s]; }
        const float inv = 1.0f / sum;

        // ---- mix: thread tid owns half2 slice `tid` (lane-consecutive, conflict-free) ----
        float ax = 0.0f, ay = 0.0f;
        #pragma unroll
        for (int s = 0; s < NSRC; ++s) {
            const half2_t h = __builtin_bit_cast(half2_t, buf[c][s][tid]);
            ax += w[s] * (float)h.x;
            ay += w[s] * (float)h.y;
        }
        float2 r;
        r.x = ax * inv;
        r.y = ay * inv;
        reinterpret_cast<float2*>(out + (size_t)bt * ND)[tid] = r;
    };

    for (int tt = 0; tt < TILES; tt += 2) {
        body(tt,     rA, rB);
        body(tt + 1, rB, rA);
    }
}

extern "C" void kernel_launch(void* const* d_in, const int* in_sizes, int n_in,
                              void* d_out, int out_size, void* d_ws, size_t ws_size,
                              hipStream_t stream) {
    const float* q    = (const float*)d_in[0];   // [D] fp32
    const float* bank = (const float*)d_in[1];   // [S,B,T,D] fp32
    float* out        = (float*)d_out;           // [B,T,D] fp32

    dim3 grid(NBLK);
    dim3 block(1024);
    dar_persist_kernel<<<grid, block, 0, stream>>>(q, bank, out);
}

// Round 5
// 115.043 us; speedup vs baseline: 1.0641x; 1.0641x over previous
//
#include <hip/hip_runtime.h>

// DepthAttentionResidual: S=16, B=4, T=1024, D=2048, fp32 in/out.
// Register-resident single-pass: one block of 512 threads per (b,t).
// Thread tid owns float4 d-slice `tid` across ALL 16 sources (64 VGPRs of
// data). Bank read from HBM exactly once, directly into registers — no LDS
// data staging, no fp16 round-trip. LDS only holds 8x16 float2 partials.
//   scores: per-thread (sum x^2, sum q*x) -> 64-lane butterfly -> per-wave
//           partials in LDS -> barrier -> redundant per-wave final reduce
//   softmax over 16 sources in a 16-lane shfl group; weights via __shfl
//   mix: 16 register FMAs per float4 component; fp32-exact output.

#define NSRC 16
#define NB   4
#define NT   1024
#define ND   2048

__global__ __launch_bounds__(512, 4)
void dar_reg_kernel(const float* __restrict__ q,
                    const float* __restrict__ bank,
                    float* __restrict__ out) {
    __shared__ float2 red[8][NSRC];   // [wave][source] = (p2, pq) per-wave partials

    const int tid  = threadIdx.x;     // 0..511
    const int wave = tid >> 6;        // 0..7
    const int lane = tid & 63;
    const int bt   = blockIdx.x;      // b*NT + t

    const float4* bt_base = reinterpret_cast<const float4*>(bank)
                          + (size_t)bt * (ND / 4) + tid;
    const float4 qv = reinterpret_cast<const float4*>(q)[tid];

    // ---- Load all 16 source slices (coalesced float4, 16 loads in flight) ----
    float4 xs[NSRC];
    #pragma unroll
    for (int s = 0; s < NSRC; ++s)
        xs[s] = bt_base[(size_t)s * (NB * NT) * (ND / 4)];

    // ---- Per-source partials + 64-lane butterfly; lane 0 posts to LDS ----
    #pragma unroll
    for (int s = 0; s < NSRC; ++s) {
        const float4 v = xs[s];
        float p2 = v.x * v.x + v.y * v.y + v.z * v.z + v.w * v.w;
        float pq = qv.x * v.x + qv.y * v.y + qv.z * v.z + qv.w * v.w;
        #pragma unroll
        for (int m = 32; m >= 1; m >>= 1) {
            p2 += __shfl_xor(p2, m, 64);
            pq += __shfl_xor(pq, m, 64);
        }
        if (lane == 0) red[wave][s] = make_float2(p2, pq);
    }
    __syncthreads();

    // ---- Final reduce (redundant per wave): lane l handles source l&15 ----
    const int sl = lane & 15;
    float p2 = 0.0f, pq = 0.0f;
    #pragma unroll
    for (int w = 0; w < 8; ++w) {
        const float2 r = red[w][sl];
        p2 += r.x;
        pq += r.y;
    }
    const float score = pq * rsqrtf(p2 * (1.0f / ND) + 1.1920928955078125e-07f)
                      * 0.022097086912079608f;   // 1/sqrt(2048)

    // ---- Softmax over the 16-lane group ----
    float mx = score;
    #pragma unroll
    for (int m = 1; m <= 8; m <<= 1) mx = fmaxf(mx, __shfl_xor(mx, m, 64));
    const float es = __expf(score - mx);
    float sum = es;
    #pragma unroll
    for (int m = 1; m <= 8; m <<= 1) sum += __shfl_xor(sum, m, 64);
    const float inv = 1.0f / sum;

    // ---- Mix from registers; weights broadcast from lanes 0..15 ----
    float4 acc = make_float4(0.0f, 0.0f, 0.0f, 0.0f);
    #pragma unroll
    for (int s = 0; s < NSRC; ++s) {
        const float ws = __shfl(es, s, 64) * inv;
        acc.x += ws * xs[s].x;
        acc.y += ws * xs[s].y;
        acc.z += ws * xs[s].z;
        acc.w += ws * xs[s].w;
    }
    reinterpret_cast<float4*>(out + (size_t)bt * ND)[tid] = acc;
}

extern "C" void kernel_launch(void* const* d_in, const int* in_sizes, int n_in,
                              void* d_out, int out_size, void* d_ws, size_t ws_size,
                              hipStream_t stream) {
    const float* q    = (const float*)d_in[0];   // [D] fp32
    const float* bank = (const float*)d_in[1];   // [S,B,T,D] fp32
    float* out        = (float*)d_out;           // [B,T,D] fp32

    dim3 grid(NB * NT);
    dim3 block(512);
    dar_reg_kernel<<<grid, block, 0, stream>>>(q, bank, out);
}